// Round 8
// baseline (162.465 us; speedup 1.0000x reference)
//
#include <hip/hip_runtime.h>

// RepeatLayers: variable-length repeat_interleave along axis 0.
// Inputs: d_in[0] = encoder_h float32 [N, D], d_in[1] = repeats int32 [N].
// Output: float32 [total_rows, D], total_rows = sum(repeats) (= out_size / D).
//
// R8: output-balanced persistent gather.
//  - Kernel A (1 block): shuffle scan + LDS scatter -> u16 idx_map (R2/R3's
//    verified-cheap version; global-scatter fallback if map > 64 KB LDS).
//  - Kernel B: 1024 persistent blocks (4/CU, full occupancy) grid-stride
//    over chunks of 4 OUTPUT rows. Every chunk is identical work (4 loads +
//    4 stores) -> no source-side imbalance. 4 row loads batched in flight.
//    Nontemporal stores: out is write-once, keeps 32 MB source in L2 so the
//    ~3.5x per-row reuse stays L2-hit.

typedef float nfloat4 __attribute__((ext_vector_type(4)));

#define SCAN_THREADS 1024
#define EPT 8                // SCAN_THREADS * EPT >= N
#define GCHUNK 4             // output rows per gather iteration
#define GBLOCKS 1024         // 4 blocks/CU -> 32 waves/CU
#define GTHREADS 256

// ---- Kernel A: scan + scatter u16 map via LDS ----
__global__ __launch_bounds__(SCAN_THREADS)
void scan_scatter_lds_kernel(const int* __restrict__ repeats,
                             unsigned short* __restrict__ idx_map,
                             int n, int total_rows) {
    extern __shared__ unsigned short lds_idx[];
    __shared__ int wsum[SCAN_THREADS / 64];
    const int t = threadIdx.x;
    const int lane = t & 63;
    const int wave = t >> 6;
    const int base = t * EPT;

    int vals[EPT];
    int s = 0;
#pragma unroll
    for (int j = 0; j < EPT; ++j) {
        const int idx = base + j;
        const int v = (idx < n) ? repeats[idx] : 0;
        vals[j] = v;
        s += v;
    }
    int isum = s;
#pragma unroll
    for (int off = 1; off < 64; off <<= 1) {
        const int v = __shfl_up(isum, off, 64);
        if (lane >= off) isum += v;
    }
    if (lane == 63) wsum[wave] = isum;
    __syncthreads();
    if (t == 0) {
        int acc = 0;
#pragma unroll
        for (int w = 0; w < SCAN_THREADS / 64; ++w) {
            const int v = wsum[w];
            wsum[w] = acc;
            acc += v;
        }
    }
    __syncthreads();
    int run = wsum[wave] + isum - s;
#pragma unroll
    for (int j = 0; j < EPT; ++j) {
        const int src_row = base + j;
        const int r = vals[j];
        for (int k = 0; k < r; ++k) lds_idx[run + k] = (unsigned short)src_row;
        run += r;
    }
    __syncthreads();
    for (int p = t; p < total_rows; p += SCAN_THREADS) idx_map[p] = lds_idx[p];
}

// ---- Fallback scan (map exceeds LDS): direct global scatter ----
__global__ __launch_bounds__(SCAN_THREADS)
void scan_scatter_global_kernel(const int* __restrict__ repeats,
                                unsigned short* __restrict__ idx_map, int n) {
    __shared__ int wsum[SCAN_THREADS / 64];
    const int t = threadIdx.x;
    const int lane = t & 63;
    const int wave = t >> 6;
    const int base = t * EPT;
    int vals[EPT];
    int s = 0;
#pragma unroll
    for (int j = 0; j < EPT; ++j) {
        const int idx = base + j;
        const int v = (idx < n) ? repeats[idx] : 0;
        vals[j] = v;
        s += v;
    }
    int isum = s;
#pragma unroll
    for (int off = 1; off < 64; off <<= 1) {
        const int v = __shfl_up(isum, off, 64);
        if (lane >= off) isum += v;
    }
    if (lane == 63) wsum[wave] = isum;
    __syncthreads();
    if (t == 0) {
        int acc = 0;
#pragma unroll
        for (int w = 0; w < SCAN_THREADS / 64; ++w) {
            const int v = wsum[w];
            wsum[w] = acc;
            acc += v;
        }
    }
    __syncthreads();
    int run = wsum[wave] + isum - s;
#pragma unroll
    for (int j = 0; j < EPT; ++j) {
        const int src_row = base + j;
        const int r = vals[j];
        for (int k = 0; k < r; ++k) idx_map[run + k] = (unsigned short)src_row;
        run += r;
    }
}

// ---- Kernel B: persistent, output-balanced gather ----
__global__ __launch_bounds__(GTHREADS)
void gather_persistent_kernel(const nfloat4* __restrict__ h,
                              const unsigned short* __restrict__ idx_map,
                              nfloat4* __restrict__ out,
                              int total_rows, int d4 /* = D/4 */) {
    const int nchunks = (total_rows + GCHUNK - 1) / GCHUNK;
    for (int c = blockIdx.x; c < nchunks; c += gridDim.x) {
        const int row0 = c * GCHUNK;
        // 4 map entries: wave-uniform addresses -> scalar broadcast loads.
        int srcs[GCHUNK];
#pragma unroll
        for (int j = 0; j < GCHUNK; ++j) {
            const int row = row0 + j;
            srcs[j] = (row < total_rows) ? (int)idx_map[row] : 0;
        }
        for (int i = threadIdx.x; i < d4; i += GTHREADS) {  // runs once (d4=256)
            nfloat4 v[GCHUNK];
#pragma unroll
            for (int j = 0; j < GCHUNK; ++j)   // 4 independent loads in flight
                v[j] = h[(size_t)srcs[j] * d4 + i];
#pragma unroll
            for (int j = 0; j < GCHUNK; ++j) {
                const int row = row0 + j;
                if (row < total_rows)
                    __builtin_nontemporal_store(v[j], &out[(size_t)row * d4 + i]);
            }
        }
    }
}

extern "C" void kernel_launch(void* const* d_in, const int* in_sizes, int n_in,
                              void* d_out, int out_size, void* d_ws, size_t ws_size,
                              hipStream_t stream) {
    const float* encoder_h = (const float*)d_in[0];
    const int*   repeats   = (const int*)d_in[1];
    float*       out       = (float*)d_out;

    const int n = in_sizes[1];            // 8192 source rows
    const int d = in_sizes[0] / n;        // 1024 features
    const int total_rows = out_size / d;  // sum(repeats)

    unsigned short* idx_map = (unsigned short*)d_ws;

    const size_t lds_bytes = ((size_t)total_rows * 2 + 3) & ~(size_t)3;
    if (lds_bytes <= 64 * 1024) {
        scan_scatter_lds_kernel<<<1, SCAN_THREADS, lds_bytes, stream>>>(
            repeats, idx_map, n, total_rows);
    } else {
        scan_scatter_global_kernel<<<1, SCAN_THREADS, 0, stream>>>(
            repeats, idx_map, n);
    }

    gather_persistent_kernel<<<GBLOCKS, GTHREADS, 0, stream>>>(
        (const nfloat4*)encoder_h, idx_map, (nfloat4*)out, total_rows, d / 4);
}

// Round 9
// 155.737 us; speedup vs baseline: 1.0432x; 1.0432x over previous
//
#include <hip/hip_runtime.h>

// RepeatLayers: variable-length repeat_interleave along axis 0.
// Inputs: d_in[0] = encoder_h float32 [N, D], d_in[1] = repeats int32 [N].
// Output: float32 [total_rows, D], total_rows = sum(repeats).
//
// R9: R7's fused source-side spread + DYNAMIC chunk scheduling.
// Static assignment ends at the slowest CU (~1.31x mean: per-CU store work
// is a sum of 32 iid U{0..7}; max over 256 CUs ~ mu+2.7sigma). 1024
// persistent blocks now pull 4-source-row chunks from a global atomic
// ticket (in d_ws, zeroed by a 4-byte hipMemsetAsync — graph-safe, the
// harness itself uses memsetAsync). Imbalance -> last-chunk tail only.
// R8's map/NT/two-kernel path regressed — reverted.

typedef float nfloat4 __attribute__((ext_vector_type(4)));

#define BLOCK 256
#define CHUNK 4              // source rows per work item
#define NBLOCKS 1024         // persistent: 4 blocks/CU

__global__ __launch_bounds__(BLOCK)
void spread_dynamic_kernel(const nfloat4* __restrict__ h,
                           const int* __restrict__ repeats,
                           nfloat4* __restrict__ out,
                           int* __restrict__ ticket,
                           int n, int d4 /* = D/4 */) {
    __shared__ int s_chunk;
    __shared__ int wpart[BLOCK / 64];
    const int t = threadIdx.x;
    const int lane = t & 63;
    const int wave = t >> 6;
    const int nchunks = (n + CHUNK - 1) / CHUNK;
    const int4* rp4 = (const int4*)repeats;

    for (;;) {
        if (t == 0) s_chunk = atomicAdd(ticket, 1);
        __syncthreads();                 // (A) publish s_chunk
        const int c = s_chunk;
        if (c >= nchunks) return;
        const int rbase = c * CHUNK;

        // ---- exclusive prefix: obase = sum(repeats[0..rbase)) ----
        // rbase/4 == c int4 elements; <=8 L2-hit loads/thread (repeats is
        // 32 KB, L1/L2 resident after first touch).
        int local = 0;
        for (int q = t; q < c; q += BLOCK) {
            const int4 v = rp4[q];
            local += v.x + v.y + v.z + v.w;
        }
#pragma unroll
        for (int off = 32; off > 0; off >>= 1)
            local += __shfl_down(local, off, 64);
        if (lane == 0) wpart[wave] = local;
        __syncthreads();                 // (B) publish wpart
        const int obase = wpart[0] + wpart[1] + wpart[2] + wpart[3];

        // ---- own chunk metadata ----
        int reps[CHUNK];
        if (rbase + CHUNK <= n) {
            const int4 r4 = *(const int4*)(repeats + rbase);
            reps[0] = r4.x; reps[1] = r4.y; reps[2] = r4.z; reps[3] = r4.w;
        } else {
#pragma unroll
            for (int j = 0; j < CHUNK; ++j)
                reps[j] = (rbase + j < n) ? repeats[rbase + j] : 0;
        }
        int offs[CHUNK];
        offs[0] = obase;
#pragma unroll
        for (int j = 1; j < CHUNK; ++j) offs[j] = offs[j - 1] + reps[j - 1];

        // ---- payload: batched independent row loads, then all stores ----
        for (int i = t; i < d4; i += BLOCK) {    // runs once (d4 == 256)
            nfloat4 v[CHUNK];
#pragma unroll
            for (int j = 0; j < CHUNK; ++j) {
                if (reps[j] > 0)                 // wave-uniform branch
                    v[j] = h[(size_t)(rbase + j) * d4 + i];
            }
#pragma unroll
            for (int j = 0; j < CHUNK; ++j) {
                const int r = reps[j];
                nfloat4* __restrict__ dst = out + (size_t)offs[j] * d4 + i;
                for (int k = 0; k < r; ++k)
                    dst[(size_t)k * d4] = v[j];  // contiguous 4 KB row stores
            }
        }
        // next iteration's (A) barrier orders s_chunk/wpart reuse
    }
}

extern "C" void kernel_launch(void* const* d_in, const int* in_sizes, int n_in,
                              void* d_out, int out_size, void* d_ws, size_t ws_size,
                              hipStream_t stream) {
    const float* encoder_h = (const float*)d_in[0];
    const int*   repeats   = (const int*)d_in[1];
    float*       out       = (float*)d_out;

    const int n = in_sizes[1];            // 8192 source rows
    const int d = in_sizes[0] / n;        // 1024 features

    int* ticket = (int*)d_ws;
    hipMemsetAsync(ticket, 0, sizeof(int), stream);  // graph-capture-safe

    const int nchunks = (n + CHUNK - 1) / CHUNK;
    const int grid = nchunks < NBLOCKS ? nchunks : NBLOCKS;
    spread_dynamic_kernel<<<grid, BLOCK, 0, stream>>>(
        (const nfloat4*)encoder_h, repeats, (nfloat4*)out, ticket, n, d / 4);
}

// Round 10
// 140.887 us; speedup vs baseline: 1.1532x; 1.1054x over previous
//
#include <hip/hip_runtime.h>

// RepeatLayers: variable-length repeat_interleave along axis 0.
// Inputs: d_in[0] = encoder_h float32 [N, D], d_in[1] = repeats int32 [N].
// Output: float32 [total_rows, D], total_rows = sum(repeats).
//
// R10: R7's fused static spread (best so far, 144 us) with:
//  - CHUNK=2 / 4096 blocks: the HW dispatcher re-balances at block
//    granularity once blocks >> co-resident slots; finer chunks halve the
//    slow-CU tail. (R9's software ticket regressed: atomics + extra barrier
//    duplicated what the dispatcher already does.)
//  - Row loads issued BEFORE the prefix-sum prologue: loads depend only on
//    rbase, so their ~900-cyc HBM latency overlaps the prologue compute.
//  - No d_ws use, no atomics, single kernel, no dependency edges.

typedef float nfloat4 __attribute__((ext_vector_type(4)));

#define CHUNK 2
#define BLOCK 256

__global__ __launch_bounds__(BLOCK)
void spread_fused_kernel(const nfloat4* __restrict__ h,
                         const int* __restrict__ repeats,
                         nfloat4* __restrict__ out,
                         int n, int d4 /* = D/4 */) {
    const int c = blockIdx.x;
    const int rbase = c * CHUNK;
    const int t = threadIdx.x;
    const int lane = t & 63;
    const int wave = t >> 6;

    // ---- 1. own repeat counts (one broadcast int2) ----
    int reps[CHUNK];
    if (rbase + CHUNK <= n) {
        const int2 r2 = *(const int2*)(repeats + rbase);
        reps[0] = r2.x; reps[1] = r2.y;
    } else {
#pragma unroll
        for (int j = 0; j < CHUNK; ++j)
            reps[j] = (rbase + j < n) ? repeats[rbase + j] : 0;
    }

    // ---- 2. issue payload row loads NOW (overlap prologue below) ----
    // d4 == BLOCK for this problem; i-loop runs exactly once.
    const int i = t;  // d4 == 256 == BLOCK (guarded by launch config)
    nfloat4 v[CHUNK];
#pragma unroll
    for (int j = 0; j < CHUNK; ++j) {
        if (reps[j] > 0)                       // wave-uniform branch
            v[j] = h[(size_t)(rbase + j) * d4 + i];
    }

    // ---- 3. prologue: obase = sum(repeats[0..rbase)), rbase = 2c ----
    __shared__ int wpart[BLOCK / 64];
    int local = 0;
    {
        const int2* rp2 = (const int2*)repeats;
        for (int q = t; q < c; q += BLOCK) {   // <=16 L2-hit int2 loads/thread
            const int2 w = rp2[q];
            local += w.x + w.y;
        }
    }
#pragma unroll
    for (int off = 32; off > 0; off >>= 1)
        local += __shfl_down(local, off, 64);
    if (lane == 0) wpart[wave] = local;
    __syncthreads();
    const int obase = wpart[0] + wpart[1] + wpart[2] + wpart[3];

    int offs[CHUNK];
    offs[0] = obase;
#pragma unroll
    for (int j = 1; j < CHUNK; ++j) offs[j] = offs[j - 1] + reps[j - 1];

    // ---- 4. stores: up to ~14 independent contiguous 4 KB row stores ----
#pragma unroll
    for (int j = 0; j < CHUNK; ++j) {
        const int r = reps[j];
        nfloat4* __restrict__ dst = out + (size_t)offs[j] * d4 + i;
        for (int k = 0; k < r; ++k)
            dst[(size_t)k * d4] = v[j];
    }
}

// Generic fallback if d4 != BLOCK (not hit for this problem's shapes).
__global__ __launch_bounds__(BLOCK)
void spread_fused_generic_kernel(const nfloat4* __restrict__ h,
                                 const int* __restrict__ repeats,
                                 nfloat4* __restrict__ out,
                                 int n, int d4) {
    const int c = blockIdx.x;
    const int rbase = c * CHUNK;
    const int t = threadIdx.x;
    const int lane = t & 63;
    const int wave = t >> 6;

    int reps[CHUNK];
#pragma unroll
    for (int j = 0; j < CHUNK; ++j)
        reps[j] = (rbase + j < n) ? repeats[rbase + j] : 0;

    __shared__ int wpart[BLOCK / 64];
    int local = 0;
    const int2* rp2 = (const int2*)repeats;
    for (int q = t; q < c; q += BLOCK) {
        const int2 w = rp2[q];
        local += w.x + w.y;
    }
#pragma unroll
    for (int off = 32; off > 0; off >>= 1)
        local += __shfl_down(local, off, 64);
    if (lane == 0) wpart[wave] = local;
    __syncthreads();
    const int obase = wpart[0] + wpart[1] + wpart[2] + wpart[3];

    int offs[CHUNK];
    offs[0] = obase;
#pragma unroll
    for (int j = 1; j < CHUNK; ++j) offs[j] = offs[j - 1] + reps[j - 1];

    for (int i = t; i < d4; i += BLOCK) {
        nfloat4 v[CHUNK];
#pragma unroll
        for (int j = 0; j < CHUNK; ++j)
            if (reps[j] > 0) v[j] = h[(size_t)(rbase + j) * d4 + i];
#pragma unroll
        for (int j = 0; j < CHUNK; ++j) {
            const int r = reps[j];
            nfloat4* __restrict__ dst = out + (size_t)offs[j] * d4 + i;
            for (int k = 0; k < r; ++k)
                dst[(size_t)k * d4] = v[j];
        }
    }
}

extern "C" void kernel_launch(void* const* d_in, const int* in_sizes, int n_in,
                              void* d_out, int out_size, void* d_ws, size_t ws_size,
                              hipStream_t stream) {
    const float* encoder_h = (const float*)d_in[0];
    const int*   repeats   = (const int*)d_in[1];
    float*       out       = (float*)d_out;

    const int n = in_sizes[1];            // 8192 source rows
    const int d = in_sizes[0] / n;        // 1024 features
    const int d4 = d / 4;

    const int nblocks = (n + CHUNK - 1) / CHUNK;   // 4096
    if (d4 == BLOCK) {
        spread_fused_kernel<<<nblocks, BLOCK, 0, stream>>>(
            (const nfloat4*)encoder_h, repeats, (nfloat4*)out, n, d4);
    } else {
        spread_fused_generic_kernel<<<nblocks, BLOCK, 0, stream>>>(
            (const nfloat4*)encoder_h, repeats, (nfloat4*)out, n, d4);
    }
}